// Round 9
// baseline (54668.591 us; speedup 1.0000x reference)
//
#include <hip/hip_runtime.h>
#include <hip/hip_bf16.h>

#define T_STEPS 4096
#define HID 2048
#define EMB 512
#define NCH 256

typedef unsigned long long u64;
typedef unsigned int u32;

__device__ __forceinline__ float sigm_f(float x) {
    x = fminf(fmaxf(x, -30.f), 30.f);
    return 1.f / (1.f + __expf(-x));
}
__device__ __forceinline__ float tanh_f(float x) {
    float ax = fminf(fabsf(x), 15.f);
    float e = __expf(2.f * ax);
    float t = (e - 1.f) / (e + 1.f);
    return copysignf(t, x);
}

// A1: per-char input projection P[c][j][g] = b_g[j] + emb[c]·Wg[0:512][j]
__global__ __launch_bounds__(256) void a1_proj(
    const float* __restrict__ emb,
    const float* __restrict__ Wf, const float* __restrict__ bf,
    const float* __restrict__ Wi, const float* __restrict__ bi,
    const float* __restrict__ Wo, const float* __restrict__ bo,
    const float* __restrict__ Wc, const float* __restrict__ bc,
    float* __restrict__ P) {
    const int g = blockIdx.x & 3;
    const int c0 = (blockIdx.x >> 2) << 3;
    const float* W = (g == 0) ? Wf : (g == 1) ? Wi : (g == 2) ? Wo : Wc;
    const float* b = (g == 0) ? bf : (g == 1) ? bi : (g == 2) ? bo : bc;
    __shared__ float el[8][EMB];
    const int tid = threadIdx.x;
    for (int q = tid; q < 8 * EMB; q += 256)
        el[q >> 9][q & 511] = emb[(size_t)(c0 + (q >> 9)) * EMB + (q & 511)];
    __syncthreads();
    float acc[8][8];
#pragma unroll
    for (int cc = 0; cc < 8; ++cc)
#pragma unroll
        for (int k = 0; k < 8; ++k) acc[cc][k] = 0.f;
    for (int e = 0; e < EMB; ++e) {
        float w8[8];
#pragma unroll
        for (int k = 0; k < 8; ++k) w8[k] = W[(size_t)e * HID + tid + (k << 8)];
#pragma unroll
        for (int cc = 0; cc < 8; ++cc) {
            float xe = el[cc][e];
#pragma unroll
            for (int k = 0; k < 8; ++k) acc[cc][k] = fmaf(xe, w8[k], acc[cc][k]);
        }
    }
    float bb[8];
#pragma unroll
    for (int k = 0; k < 8; ++k) bb[k] = b[tid + (k << 8)];
#pragma unroll
    for (int cc = 0; cc < 8; ++cc)
#pragma unroll
        for (int k = 0; k < 8; ++k)
            P[((((size_t)(c0 + cc) << 11) + tid + (k << 8)) << 2) + g] = acc[cc][k] + bb[k];
}

// A2: transpose recurrent weights -> WT[g][j][k] (k contiguous)
__global__ void a2_transpose(const float* __restrict__ Wf, const float* __restrict__ Wi,
                             const float* __restrict__ Wo, const float* __restrict__ Wc,
                             float* __restrict__ WT) {
    __shared__ float tile[32][33];
    const int g = blockIdx.z;
    const float* W = (g == 0) ? Wf : (g == 1) ? Wi : (g == 2) ? Wo : Wc;
    const int k0 = blockIdx.x << 5, j0 = blockIdx.y << 5;
    const int tx = threadIdx.x, ty = threadIdx.y;
#pragma unroll
    for (int i = 0; i < 32; i += 8)
        tile[ty + i][tx] = W[(size_t)(EMB + k0 + ty + i) * HID + j0 + tx];
    __syncthreads();
#pragma unroll
    for (int i = 0; i < 32; i += 8)
        WT[(((size_t)g * HID + j0 + ty + i) << 11) + k0 + tx] = tile[tx][ty + i];
}

// A3: init h buffer 0 with tag 0 and h0 values
__global__ void a3_init(const float* __restrict__ hidden, u64* __restrict__ hbuf) {
    int j = blockIdx.x * 256 + threadIdx.x;
    if (j < HID) hbuf[j] = (u64)__float_as_uint(hidden[j]);  // hi=tag 0
}

#define HLOAD(p) __hip_atomic_load((p), __ATOMIC_RELAXED, __HIP_MEMORY_SCOPE_SYSTEM)

// B: persistent recurrence, barrier-free step loop.
// - Wave q stages mailbox chunk q (256 tagged u64, all-or-nothing wave vote)
//   into h_lds[buf], then stamps LDS rdy[buf][q]=s (monotone; no resets).
// - Consumers spin on LDS stamps per chunk (rotated order, own chunk first);
//   waves free-run across steps (skew<=1 proven by the publish dependency
//   chain: any tag s+2 requires every block consumed s+1, which requires
//   every wave here finished s).
// - Publish: LDS pubstamp rendezvous (wave 0), then ONE 64B system store
//   (R7 mechanics: one write/invalidate/refill per line per step).
// - Fused output projection: out[t][b] = h_t · Wout[:,b] + bout[b] computed
//   from staged chunks (4 MAC/lane, butterflied with the gate reduce);
//   c_out kernel and the hs trace are eliminated. Iter s==T stages tag T
//   and emits the last row only.
__global__ __launch_bounds__(512, 2) void b_lstm(
    const int* __restrict__ seq, const float* __restrict__ cell,
    const float* __restrict__ P, const float* __restrict__ WT,
    const float* __restrict__ Wout, const float* __restrict__ bout,
    u64* __restrict__ hbuf, float* __restrict__ out) {
    __shared__ float h_lds[2][HID];
    __shared__ int seq_lds[T_STEPS];
    __shared__ int rdy[2][8];
    __shared__ int pubstamp[8];
    __shared__ float h_pubv[8];
    __shared__ float outpart[8];
    const int tid = threadIdx.x;
    const int l = tid & 63;
    const int jl = tid >> 6;
    const int b = blockIdx.x;
    const int jglob = (b << 3) + jl;

    for (int q = tid; q < T_STEPS; q += 512) seq_lds[q] = seq[q];
    if (tid < 16) rdy[tid >> 3][tid & 7] = -1;
    if (tid < 8) pubstamp[tid] = -1;

    // per-thread k-ownership: k = q*256 + 4*l + r  (q=0..7, r=0..3)
    float4 wreg[4][8];
#pragma unroll
    for (int g = 0; g < 4; ++g)
#pragma unroll
        for (int q = 0; q < 8; ++q)
            wreg[g][q] = *(const float4*)&WT[(((size_t)g * HID + jglob) << 11) + (q << 8) + (l << 2)];

    float4 wout4;
    {
        const int kb = (jl << 8) + (l << 2);
        wout4.x = Wout[(size_t)(kb + 0) * NCH + b];
        wout4.y = Wout[(size_t)(kb + 1) * NCH + b];
        wout4.z = Wout[(size_t)(kb + 2) * NCH + b];
        wout4.w = Wout[(size_t)(kb + 3) * NCH + b];
    }
    const float bout_b = bout[b];

    float c_reg = cell[jglob];
    float h_last = 0.f;
    __syncthreads();   // the ONLY block-wide barrier

    for (int s = 0; s <= T_STEPS; ++s) {
        const int buf = s & 1;
        float4 xg = make_float4(0.f, 0.f, 0.f, 0.f);
        if (s < T_STEPS) {
            const int ch = seq_lds[s];
            xg = *(const float4*)(P + ((((size_t)ch << 11) + jglob) << 2));
        }

        // ---- stage my chunk jl: entries jl*256 + 4l + {0..3} ----
        const u64* src = hbuf + ((size_t)buf << 11) + (jl << 8) + (l << 2);
        const u32 target = (u32)s;
        u64 t0, t1, t2, t3;
        for (;;) {
            t0 = HLOAD(src + 0);
            t1 = HLOAD(src + 1);
            t2 = HLOAD(src + 2);
            t3 = HLOAD(src + 3);
            u32 bad = ((u32)(t0 >> 32) ^ target) | ((u32)(t1 >> 32) ^ target) |
                      ((u32)(t2 >> 32) ^ target) | ((u32)(t3 >> 32) ^ target);
            if (__all(bad == 0)) break;
        }
        float4 hv;
        hv.x = __uint_as_float((u32)t0);
        hv.y = __uint_as_float((u32)t1);
        hv.z = __uint_as_float((u32)t2);
        hv.w = __uint_as_float((u32)t3);
        *(float4*)&h_lds[buf][(jl << 8) + (l << 2)] = hv;
        __threadfence_block();
        if (l == 0) ((volatile int*)rdy[buf])[jl] = s;

        // fused out-projection partial for row s-1 (staged data = hs[s-1])
        float od = hv.x * wout4.x + hv.y * wout4.y + hv.z * wout4.z + hv.w * wout4.w;

        float a0 = 0.f, a1 = 0.f, a2 = 0.f, a3 = 0.f;
        if (s < T_STEPS) {
#pragma unroll
            for (int qq = 0; qq < 8; ++qq) {
                const int q = (jl + qq) & 7;
                if (qq) { while (((volatile int*)rdy[buf])[q] < s) {} }
                const float4 h4 = *(const float4*)&h_lds[buf][(q << 8) + (l << 2)];
                a0 = fmaf(wreg[0][q].x, h4.x, a0);
                a0 = fmaf(wreg[0][q].y, h4.y, a0);
                a0 = fmaf(wreg[0][q].z, h4.z, a0);
                a0 = fmaf(wreg[0][q].w, h4.w, a0);
                a1 = fmaf(wreg[1][q].x, h4.x, a1);
                a1 = fmaf(wreg[1][q].y, h4.y, a1);
                a1 = fmaf(wreg[1][q].z, h4.z, a1);
                a1 = fmaf(wreg[1][q].w, h4.w, a1);
                a2 = fmaf(wreg[2][q].x, h4.x, a2);
                a2 = fmaf(wreg[2][q].y, h4.y, a2);
                a2 = fmaf(wreg[2][q].z, h4.z, a2);
                a2 = fmaf(wreg[2][q].w, h4.w, a2);
                a3 = fmaf(wreg[3][q].x, h4.x, a3);
                a3 = fmaf(wreg[3][q].y, h4.y, a3);
                a3 = fmaf(wreg[3][q].z, h4.z, a3);
                a3 = fmaf(wreg[3][q].w, h4.w, a3);
            }
        }
#pragma unroll
        for (int off = 32; off > 0; off >>= 1) {
            a0 += __shfl_xor(a0, off, 64);
            a1 += __shfl_xor(a1, off, 64);
            a2 += __shfl_xor(a2, off, 64);
            a3 += __shfl_xor(a3, off, 64);
            od += __shfl_xor(od, off, 64);
        }
        if (s < T_STEPS) {
            const float f = sigm_f(a0 + xg.x);
            const float ii = sigm_f(a1 + xg.y);
            const float oo = sigm_f(a2 + xg.z);
            const float gg = tanh_f(a3 + xg.w);
            c_reg = fmaf(f, c_reg, ii * gg);
            h_last = oo * tanh_f(c_reg);   // identical in all lanes
        }
        if (l == 0) {
            h_pubv[jl] = h_last;
            outpart[jl] = od;
            __threadfence_block();
            ((volatile int*)pubstamp)[jl] = s;
        }
        if (jl == 0) {
            // rendezvous on LDS stamps (replaces __syncthreads)
            for (;;) {
                int v = ((volatile int*)pubstamp)[l & 7];
                if (__all(v >= s)) break;
            }
            if (s < T_STEPS && l < 8) {
                float hp = ((volatile float*)h_pubv)[l];
                u64 pv = ((u64)(u32)(s + 1) << 32) | (u64)__float_as_uint(hp);
                __hip_atomic_store(hbuf + ((size_t)((s + 1) & 1) << 11) + (b << 3) + l,
                                   pv, __ATOMIC_RELAXED, __HIP_MEMORY_SCOPE_SYSTEM);
            }
            if (s >= 1 && l == 0) {
                float oa = bout_b;
#pragma unroll
                for (int i = 0; i < 8; ++i) oa += ((volatile float*)outpart)[i];
                out[(size_t)(s - 1) * NCH + b] = oa;
            }
        }
    }
    if (l == 0) {
        out[(size_t)T_STEPS * NCH + jglob] = h_last;          // h_fin
        out[(size_t)T_STEPS * NCH + HID + jglob] = c_reg;     // c_fin
    }
}

extern "C" void kernel_launch(void* const* d_in, const int* in_sizes, int n_in,
                              void* d_out, int out_size, void* d_ws, size_t ws_size,
                              hipStream_t stream) {
    const int* seq = (const int*)d_in[0];
    const float* hidden = (const float*)d_in[1];
    const float* cell = (const float*)d_in[2];
    const float* emb = (const float*)d_in[3];
    const float* Wf = (const float*)d_in[4];
    const float* bf = (const float*)d_in[5];
    const float* Wi = (const float*)d_in[6];
    const float* bi = (const float*)d_in[7];
    const float* Wo = (const float*)d_in[8];
    const float* bo = (const float*)d_in[9];
    const float* Wc = (const float*)d_in[10];
    const float* bc = (const float*)d_in[11];
    const float* Wout = (const float*)d_in[12];
    const float* bout = (const float*)d_in[13];
    float* out = (float*)d_out;

    // ws layout (floats): hbuf(2*2048 u64 = 8192 f) | WT(16.78M) | P(2.10M)
    float* wsf = (float*)d_ws;
    u64* hbuf = (u64*)d_ws;
    float* WT = wsf + 8192;
    float* P = WT + (size_t)4 * HID * HID;

    a1_proj<<<128, 256, 0, stream>>>(emb, Wf, bf, Wi, bi, Wo, bo, Wc, bc, P);
    a2_transpose<<<dim3(64, 64, 4), dim3(32, 8), 0, stream>>>(Wf, Wi, Wo, Wc, WT);
    a3_init<<<8, 256, 0, stream>>>(hidden, hbuf);
    b_lstm<<<256, 512, 0, stream>>>(seq, cell, P, WT, Wout, bout, hbuf, out);
}